// Round 10
// baseline (208.886 us; speedup 1.0000x reference)
//
#include <hip/hip_runtime.h>

#define NTOK 65536
#define DIM 256
#define KC 1024
#define EPS 0.08f

typedef __attribute__((ext_vector_type(8))) _Float16 f16x8;
typedef __attribute__((ext_vector_type(8))) unsigned short u16x8;
typedef __attribute__((ext_vector_type(4))) float f32x4;

static __device__ __forceinline__ unsigned short f16bits(float f) {
  _Float16 h = (_Float16)f;
  return __builtin_bit_cast(unsigned short, h);
}

// ---- e: fp32 -> fp16 FRAGMENT-MAJOR global image + esq; zero scalars ----
// Chunk c = ct*64 + s*8 + nj (1 KB each): lane = kq*16+col holds
// e[ct*128 + nj*16 + col][s*32 + kq*8 + j], j=0..7, as 8 f16.
__global__ __launch_bounds__(256) void vq_prep_e(const float* __restrict__ e,
                                                 unsigned short* __restrict__ eg,
                                                 float* __restrict__ esq,
                                                 int* __restrict__ hist,
                                                 int* __restrict__ fixCount) {
  const int gid = blockIdx.x * 256 + threadIdx.x;  // 32768 work items
  const int t = gid >> 5;   // code row 0..1023
  const int o = gid & 31;   // k-octet 0..31
  const float4 v0 = *reinterpret_cast<const float4*>(&e[t * DIM + o * 8]);
  const float4 v1 = *reinterpret_cast<const float4*>(&e[t * DIM + o * 8 + 4]);
  u16x8 u;
  u[0] = f16bits(v0.x); u[1] = f16bits(v0.y); u[2] = f16bits(v0.z); u[3] = f16bits(v0.w);
  u[4] = f16bits(v1.x); u[5] = f16bits(v1.y); u[6] = f16bits(v1.z); u[7] = f16bits(v1.w);
  const int ct = t >> 7, nj = (t >> 4) & 7, col = t & 15;
  const int s = o >> 2, kq = o & 3;
  char* dst = (char*)eg + ((ct * 64 + s * 8 + nj) << 10) + ((kq * 16 + col) << 4);
  *reinterpret_cast<u16x8*>(dst) = u;
  float p = v0.x * v0.x + v0.y * v0.y + v0.z * v0.z + v0.w * v0.w +
            v1.x * v1.x + v1.y * v1.y + v1.z * v1.z + v1.w * v1.w;
#pragma unroll
  for (int m = 16; m > 0; m >>= 1) p += __shfl_xor(p, m, 64);
  if (o == 0) esq[t] = p;
  if (blockIdx.x < 4) hist[blockIdx.x * 256 + threadIdx.x] = 0;
  if (gid == 0) *fixCount = 0;
}

// ---- 4-wave blocks, wave = 16 tokens x 1024 codes; b double-buffered ----
__global__ __launch_bounds__(256, 3) void vq_argmin(
    const float* __restrict__ x, const unsigned short* __restrict__ eg,
    const float* __restrict__ esq, const float* __restrict__ e,
    float* __restrict__ outIdxF, float* __restrict__ outQ,
    float* __restrict__ bestDist, float* __restrict__ xsq,
    int* __restrict__ hist, int* __restrict__ fixCount,
    unsigned int* __restrict__ fixList) {
  const int lane = threadIdx.x & 63, w = threadIdx.x >> 6;
  const int col = lane & 15, kq = lane >> 4;
  const int tw = blockIdx.x * 64 + w * 16;  // this wave's 16 tokens

  // prologue: x -> A-fragments (lane holds token tw+col, k = s*32+kq*8+j)
  f16x8 a[8];
  float sq = 0.f;
#pragma unroll
  for (int s = 0; s < 8; ++s) {
    const float* xp = &x[(tw + col) * DIM + s * 32 + kq * 8];
    const float4 v0 = *reinterpret_cast<const float4*>(xp);
    const float4 v1 = *reinterpret_cast<const float4*>(xp + 4);
    a[s][0] = (_Float16)v0.x; a[s][1] = (_Float16)v0.y;
    a[s][2] = (_Float16)v0.z; a[s][3] = (_Float16)v0.w;
    a[s][4] = (_Float16)v1.x; a[s][5] = (_Float16)v1.y;
    a[s][6] = (_Float16)v1.z; a[s][7] = (_Float16)v1.w;
    sq += v0.x * v0.x + v0.y * v0.y + v0.z * v0.z + v0.w * v0.w +
          v1.x * v1.x + v1.y * v1.y + v1.z * v1.z + v1.w * v1.w;
  }
  sq += __shfl_xor(sq, 16, 64);
  sq += __shfl_xor(sq, 32, 64);
  if (lane < 16) xsq[tw + lane] = sq;

  auto LD8 = [&](f16x8 (&buf)[8], const char* eb, int s) {
#pragma unroll
    for (int nj = 0; nj < 8; ++nj)
      buf[nj] = *reinterpret_cast<const f16x8*>(
          eb + ((s * 8 + nj) << 10) + (lane << 4));
  };
  auto MF8 = [&](const f16x8& av, f16x8 (&buf)[8], f32x4 (&acc)[8]) {
#pragma unroll
    for (int nj = 0; nj < 8; ++nj)
      acc[nj] = __builtin_amdgcn_mfma_f32_16x16x32_f16(av, buf[nj], acc[nj], 0, 0, 0);
  };

  // per-lane top-3 (values) + top-2 indices, per accumulator row r
  float v1_[4], v2_[4], v3_[4];
  int i1_[4], i2_[4];
#pragma unroll
  for (int r = 0; r < 4; ++r) {
    v1_[r] = 3.4e38f; v2_[r] = 3.4e38f; v3_[r] = 3.4e38f;
    i1_[r] = 0; i2_[r] = 0;
  }

  f16x8 bA[8], bB[8];
  LD8(bA, (const char*)eg, 0);

  for (int ct = 0; ct < 8; ++ct) {
    const char* eb = (const char*)eg + ct * 65536;
    f32x4 acc[8];
#pragma unroll
    for (int nj = 0; nj < 8; ++nj) acc[nj] = (f32x4){0.f, 0.f, 0.f, 0.f};

    // software-pipelined: always ~8 b-loads in flight under the MFMA chain
    LD8(bB, eb, 1); MF8(a[0], bA, acc);
    LD8(bA, eb, 2); MF8(a[1], bB, acc);
    LD8(bB, eb, 3); MF8(a[2], bA, acc);
    LD8(bA, eb, 4); MF8(a[3], bB, acc);
    LD8(bB, eb, 5); MF8(a[4], bA, acc);
    LD8(bA, eb, 6); MF8(a[5], bB, acc);
    LD8(bB, eb, 7); MF8(a[6], bA, acc);
    if (ct < 7) LD8(bA, eb + 65536, 0);  // cross-ct prefetch (uniform branch)
    MF8(a[7], bB, acc);

    // distances; codes ascend per lane over (ct, nj) -> strict < = first min
#pragma unroll
    for (int nj = 0; nj < 8; ++nj) {
      const int code = ct * 128 + nj * 16 + col;
      const float sqv = esq[code];
#pragma unroll
      for (int r = 0; r < 4; ++r) {
        const float d = fmaf(-2.f, acc[nj][r], sqv);
        if (d < v1_[r]) {
          v3_[r] = v2_[r]; v2_[r] = v1_[r]; i2_[r] = i1_[r];
          v1_[r] = d; i1_[r] = code;
        } else if (d < v2_[r]) {
          v3_[r] = v2_[r]; v2_[r] = d; i2_[r] = code;
        } else if (d < v3_[r]) {
          v3_[r] = d;
        }
      }
    }
  }

  // cross-lane top-3 merge over the 16 code-columns (masks 1,2,4,8)
#pragma unroll
  for (int r = 0; r < 4; ++r) {
    float mv1 = v1_[r], mv2 = v2_[r], mv3 = v3_[r];
    int mi1 = i1_[r], mi2 = i2_[r];
#pragma unroll
    for (int m = 1; m <= 8; m <<= 1) {
      const float ov1 = __shfl_xor(mv1, m, 64);
      const float ov2 = __shfl_xor(mv2, m, 64);
      const float ov3 = __shfl_xor(mv3, m, 64);
      const int oi1 = __shfl_xor(mi1, m, 64);
      const int oi2 = __shfl_xor(mi2, m, 64);
      const bool oW = (ov1 < mv1) || (ov1 == mv1 && oi1 < mi1);
      const float wv1 = oW ? ov1 : mv1, wv2 = oW ? ov2 : mv2, wv3 = oW ? ov3 : mv3;
      const int wi1 = oW ? oi1 : mi1, wi2 = oW ? oi2 : mi2;
      const float lv1 = oW ? mv1 : ov1, lv2 = oW ? mv2 : ov2;
      const int li1 = oW ? mi1 : oi1;
      const bool w2 = (wv2 < lv1) || (wv2 == lv1 && wi2 < li1);
      mv1 = wv1; mi1 = wi1;
      mv2 = w2 ? wv2 : lv1;
      mi2 = w2 ? wi2 : li1;
      mv3 = w2 ? fminf(wv3, lv1) : fminf(wv2, lv2);
    }
    if (col == 0) {
      const int t = tw + kq * 4 + r;
      outIdxF[t] = (float)mi1;
      bestDist[t] = mv1;
      atomicAdd(&hist[mi1], 1);
      if (mv2 - mv1 < EPS) {
        const unsigned full = (mv3 - mv1 < EPS) ? 0x80000000u : 0u;
        const int p = atomicAdd(fixCount, 1);
        fixList[p * 2] = (unsigned)t | full;
        fixList[p * 2 + 1] = (unsigned)mi2;
      }
    }
    i1_[r] = mi1;  // merged result, identical on all 16 lanes of the kq group
  }

  // fused gather: 16 tokens, index broadcast via shfl (no LDS, no barrier)
#pragma unroll
  for (int i = 0; i < 16; ++i) {
    const int id = __shfl(i1_[i & 3], (i >> 2) * 16, 64);
    const float4 q = reinterpret_cast<const float4*>(&e[id * DIM])[lane];
    reinterpret_cast<float4*>(&outQ[(tw + i) * DIM])[lane] = q;
  }
}

// ---- fixup: pairwise exact check (common) or full rescan (rare) ----
__global__ __launch_bounds__(256) void vq_fixup(
    const float* __restrict__ x, const float* __restrict__ e,
    const int* __restrict__ fixCount, const unsigned int* __restrict__ fixList,
    float* __restrict__ outIdxF, float* __restrict__ outQ,
    float* __restrict__ bestDist, int* __restrict__ hist) {
  const int n = *fixCount;
  const int tid = threadIdx.x;
  __shared__ float xrow[256];
  __shared__ float rv[4];
  __shared__ int ri[4];
  __shared__ int sOld, sFi;
  for (int it = blockIdx.x; it < n; it += gridDim.x) {
    const unsigned e0 = fixList[it * 2];
    const int t = (int)(e0 & 0x3FFFFFFFu);
    const bool full = (e0 >> 31) != 0u;
    if (!full) {
      // pairwise: wave 0 exactly compares rows i1 (current) and i2
      if (tid < 64) {
        const int i1 = (int)outIdxF[t];
        const int i2 = (int)fixList[it * 2 + 1];
        const float4 xv = reinterpret_cast<const float4*>(&x[t * DIM])[tid];
        const float4 e1 = reinterpret_cast<const float4*>(&e[i1 * DIM])[tid];
        const float4 e2 = reinterpret_cast<const float4*>(&e[i2 * DIM])[tid];
        float d1 = (xv.x - e1.x) * (xv.x - e1.x) + (xv.y - e1.y) * (xv.y - e1.y) +
                   (xv.z - e1.z) * (xv.z - e1.z) + (xv.w - e1.w) * (xv.w - e1.w);
        float d2 = (xv.x - e2.x) * (xv.x - e2.x) + (xv.y - e2.y) * (xv.y - e2.y) +
                   (xv.z - e2.z) * (xv.z - e2.z) + (xv.w - e2.w) * (xv.w - e2.w);
#pragma unroll
        for (int m = 32; m > 0; m >>= 1) {
          d1 += __shfl_xor(d1, m, 64);
          d2 += __shfl_xor(d2, m, 64);
        }
        const bool swap2 = (d2 < d1) || (d2 == d1 && i2 < i1);
        const int wIdx = swap2 ? i2 : i1;
        const float wD = swap2 ? d2 : d1;
        if (tid == 0) {
          bestDist[t] = wD;
          if (wIdx != i1) {
            atomicSub(&hist[i1], 1);
            atomicAdd(&hist[wIdx], 1);
            outIdxF[t] = (float)wIdx;
          }
        }
        if (swap2) {
          const float4 q = reinterpret_cast<const float4*>(&e[wIdx * DIM])[tid];
          reinterpret_cast<float4*>(&outQ[t * DIM])[tid] = q;
        }
      }
    } else {
      // full exact rescan (expected ~1-3 tokens total)
      __syncthreads();
      if (tid < 64) ((float4*)xrow)[tid] = ((const float4*)&x[t * DIM])[tid];
      __syncthreads();
      float bv = 3.4e38f; int bi = 0;
      for (int c = tid; c < KC; c += 256) {
        float s = 0.f;
#pragma unroll
        for (int d = 0; d < DIM; d += 4) {
          const float4 ev = *(const float4*)&e[c * DIM + d];
          const float d0 = xrow[d] - ev.x, d1 = xrow[d + 1] - ev.y;
          const float d2 = xrow[d + 2] - ev.z, d3 = xrow[d + 3] - ev.w;
          s += d0 * d0 + d1 * d1 + d2 * d2 + d3 * d3;
        }
        if (s < bv) { bv = s; bi = c; }  // c ascends per thread
      }
#pragma unroll
      for (int m = 1; m <= 32; m <<= 1) {
        const float ob = __shfl_xor(bv, m, 64);
        const int oi = __shfl_xor(bi, m, 64);
        if (ob < bv || (ob == bv && oi < bi)) { bv = ob; bi = oi; }
      }
      const int lane = tid & 63, wv = tid >> 6;
      if (lane == 0) { rv[wv] = bv; ri[wv] = bi; }
      __syncthreads();
      if (tid == 0) {
        float fb = rv[0]; int fi = ri[0];
        for (int k = 1; k < 4; ++k)
          if (rv[k] < fb || (rv[k] == fb && ri[k] < fi)) { fb = rv[k]; fi = ri[k]; }
        sOld = (int)outIdxF[t];
        sFi = fi;
        bestDist[t] = fb;
        if (fi != sOld) {
          atomicSub(&hist[sOld], 1);
          atomicAdd(&hist[fi], 1);
          outIdxF[t] = (float)fi;
        }
      }
      __syncthreads();
      if (sFi != sOld) outQ[t * DIM + tid] = e[sFi * DIM + tid];
      __syncthreads();
    }
  }
}

// ---- final scalars: loss from xsq+bestDist; perplexity from hist ----
__global__ __launch_bounds__(1024) void vq_final(
    const int* __restrict__ hist, const float* __restrict__ xsq,
    const float* __restrict__ bestDist, float* __restrict__ outLoss,
    float* __restrict__ outPerp) {
  const int tid = threadIdx.x;
  float ls = 0.f;
  for (int i = 0; i < 64; ++i) {
    const int t = tid + i * 1024;
    ls += xsq[t] + bestDist[t];
  }
  const float p = (float)hist[tid] * (1.f / 65536.f);
  float ent = p * logf(p + 1e-10f);
#pragma unroll
  for (int o = 32; o > 0; o >>= 1) {
    ls += __shfl_down(ls, o, 64);
    ent += __shfl_down(ent, o, 64);
  }
  __shared__ float lbuf[16], ebuf[16];
  const int lane = tid & 63, wv = tid >> 6;
  if (lane == 0) { lbuf[wv] = ls; ebuf[wv] = ent; }
  __syncthreads();
  if (tid == 0) {
    float L = 0.f, E = 0.f;
    for (int i = 0; i < 16; ++i) { L += lbuf[i]; E += ebuf[i]; }
    *outLoss = 0.25f * (L / 16777216.f);
    *outPerp = expf(-E);
  }
}

extern "C" void kernel_launch(void* const* d_in, const int* in_sizes, int n_in,
                              void* d_out, int out_size, void* d_ws, size_t ws_size,
                              hipStream_t stream) {
  const float* x = (const float*)d_in[0];  // [65536, 256]
  const float* e = (const float*)d_in[1];  // [1024, 256]
  float* out = (float*)d_out;
  float* outQ = out;                 // 16777216 floats
  float* outLoss = out + 16777216;
  float* outPerp = out + 16777217;
  float* outIdxF = out + 16777218;   // 65536 floats

  char* ws = (char*)d_ws;
  int*   hist     = (int*)ws;                     // 4 KB
  float* esq      = (float*)(ws + 4096);          // 4 KB
  float* xsq      = (float*)(ws + 8192);          // 256 KB
  float* bestDist = (float*)(ws + 270336);        // 256 KB
  int*   fixCount = (int*)(ws + 532480);          // 16 B
  unsigned int* fixList = (unsigned int*)(ws + 532496);  // 512 KB (2/entry)
  unsigned short* e_f16 = (unsigned short*)(ws + 1056784);  // 512 KB
  // total ws use ~1.57 MB

  vq_prep_e<<<128, 256, 0, stream>>>(e, e_f16, esq, hist, fixCount);
  vq_argmin<<<NTOK / 64, 256, 0, stream>>>(x, e_f16, esq, e, outIdxF, outQ,
                                           bestDist, xsq, hist, fixCount, fixList);
  vq_fixup<<<256, 256, 0, stream>>>(x, e, fixCount, fixList, outIdxF, outQ,
                                    bestDist, hist);
  vq_final<<<1, 1024, 0, stream>>>(hist, xsq, bestDist, outLoss, outPerp);
}

// Round 13
// 164.851 us; speedup vs baseline: 1.2671x; 1.2671x over previous
//
#include <hip/hip_runtime.h>

#define NTOK 65536
#define DIM 256
#define KC 1024
#define EPS 0.08f

typedef __attribute__((ext_vector_type(8))) _Float16 f16x8;
typedef __attribute__((ext_vector_type(8))) unsigned short u16x8;
typedef __attribute__((ext_vector_type(4))) float f32x4;

static __device__ __forceinline__ unsigned short f16bits(float f) {
  _Float16 h = (_Float16)f;
  return __builtin_bit_cast(unsigned short, h);
}

#define VWAIT(n) asm volatile("s_waitcnt vmcnt(" #n ")" ::: "memory")
#define SB() __builtin_amdgcn_sched_barrier(0)
#define GLDX4(dst, p, off) \
  asm volatile("global_load_dwordx4 %0, %1, off offset:" #off \
               : "=v"(dst) : "v"(p) : "memory")

// ---- e: fp32 -> fp16 FRAGMENT-MAJOR global image + esq; zero scalars ----
// Chunk c = ctk*32 + s*4 + njj (1 KB each), ctk in [0,16) over 64-code
// groups: lane = kq*16+col holds e[ctk*64 + njj*16 + col][s*32 + kq*8 + j].
__global__ __launch_bounds__(256) void vq_prep_e(const float* __restrict__ e,
                                                 unsigned short* __restrict__ eg,
                                                 float* __restrict__ esq,
                                                 int* __restrict__ hist,
                                                 int* __restrict__ fixCount) {
  const int gid = blockIdx.x * 256 + threadIdx.x;  // 32768 work items
  const int t = gid >> 5;   // code row 0..1023
  const int o = gid & 31;   // k-octet 0..31
  const float4 v0 = *reinterpret_cast<const float4*>(&e[t * DIM + o * 8]);
  const float4 v1 = *reinterpret_cast<const float4*>(&e[t * DIM + o * 8 + 4]);
  u16x8 u;
  u[0] = f16bits(v0.x); u[1] = f16bits(v0.y); u[2] = f16bits(v0.z); u[3] = f16bits(v0.w);
  u[4] = f16bits(v1.x); u[5] = f16bits(v1.y); u[6] = f16bits(v1.z); u[7] = f16bits(v1.w);
  const int ctk = t >> 6, njj = (t >> 4) & 3, col = t & 15;
  const int s = o >> 2, kq = o & 3;
  char* dst = (char*)eg + ((ctk * 32 + s * 4 + njj) << 10) + ((kq * 16 + col) << 4);
  *reinterpret_cast<u16x8*>(dst) = u;
  float p = v0.x * v0.x + v0.y * v0.y + v0.z * v0.z + v0.w * v0.w +
            v1.x * v1.x + v1.y * v1.y + v1.z * v1.z + v1.w * v1.w;
#pragma unroll
  for (int m = 16; m > 0; m >>= 1) p += __shfl_xor(p, m, 64);
  if (o == 0) esq[t] = p;
  if (blockIdx.x < 4) hist[blockIdx.x * 256 + threadIdx.x] = 0;
  if (gid == 0) *fixCount = 0;
}

// ---- 4 indep waves/block, wave = 32 tokens x 1024 codes ----
// b-feed: asm quad loads, 4-buffer rotation (compile-time buffer index),
// 16 loads in flight, counted VWAIT(12), no spill by construction.
__global__ __launch_bounds__(256, 2) void vq_argmin(
    const float* __restrict__ x, const unsigned short* __restrict__ eg,
    const float* __restrict__ esq, const float* __restrict__ e,
    float* __restrict__ outIdxF, float* __restrict__ outQ,
    float* __restrict__ bestDist, float* __restrict__ xsq,
    int* __restrict__ hist, int* __restrict__ fixCount,
    unsigned int* __restrict__ fixList) {
  const int lane = threadIdx.x & 63, w = threadIdx.x >> 6;
  const int col = lane & 15, kq = lane >> 4;
  const int tw = blockIdx.x * 128 + w * 32;  // this wave's 32 tokens

  // prologue: x -> A-fragments; token tw + mi*16 + col, k = s*32+kq*8+j
  f16x8 a[2][8];
  float sqm[2] = {0.f, 0.f};
#pragma unroll
  for (int mi = 0; mi < 2; ++mi) {
#pragma unroll
    for (int s = 0; s < 8; ++s) {
      const float* xp = &x[(tw + mi * 16 + col) * DIM + s * 32 + kq * 8];
      const float4 v0 = *reinterpret_cast<const float4*>(xp);
      const float4 v1 = *reinterpret_cast<const float4*>(xp + 4);
      a[mi][s][0] = (_Float16)v0.x; a[mi][s][1] = (_Float16)v0.y;
      a[mi][s][2] = (_Float16)v0.z; a[mi][s][3] = (_Float16)v0.w;
      a[mi][s][4] = (_Float16)v1.x; a[mi][s][5] = (_Float16)v1.y;
      a[mi][s][6] = (_Float16)v1.z; a[mi][s][7] = (_Float16)v1.w;
      sqm[mi] += v0.x * v0.x + v0.y * v0.y + v0.z * v0.z + v0.w * v0.w +
                 v1.x * v1.x + v1.y * v1.y + v1.z * v1.z + v1.w * v1.w;
    }
  }
#pragma unroll
  for (int mi = 0; mi < 2; ++mi) {
    sqm[mi] += __shfl_xor(sqm[mi], 16, 64);
    sqm[mi] += __shfl_xor(sqm[mi], 32, 64);
  }
  if (lane < 16) {
    xsq[tw + lane] = sqm[0];
    xsq[tw + 16 + lane] = sqm[1];
  }

  // per-lane top-3 values + top-2 indices, per (mi, r)
  float v1_[2][4], v2_[2][4], v3_[2][4];
  int i1_[2][4], i2_[2][4];
#pragma unroll
  for (int mi = 0; mi < 2; ++mi)
#pragma unroll
    for (int r = 0; r < 4; ++r) {
      v1_[mi][r] = 3.4e38f; v2_[mi][r] = 3.4e38f; v3_[mi][r] = 3.4e38f;
      i1_[mi][r] = 0; i2_[mi][r] = 0;
    }

  f32x4 acc[2][4];
  f16x8 B[4][4];  // 4 rotating groups x 4 fragments
  const char* p = (const char*)eg + lane * 16;  // linear walk, +4096/group

  VWAIT(0);  // drain prologue loads + xsq stores: clean vmcnt slate
  SB();
  // prime groups for steps 0..3 into bufs 0..3 (16 loads outstanding)
#pragma unroll
  for (int g = 0; g < 4; ++g) {
    GLDX4(B[g][0], p, 0); GLDX4(B[g][1], p, 1024);
    GLDX4(B[g][2], p, 2048); GLDX4(B[g][3], p, 3072);
    p += 4096;
  }

#define STEP_BODY(S, BUF)                                                     \
  do {                                                                        \
    acc[0][0] = __builtin_amdgcn_mfma_f32_16x16x32_f16(a[0][(S)], BUF[0], acc[0][0], 0, 0, 0); \
    acc[0][1] = __builtin_amdgcn_mfma_f32_16x16x32_f16(a[0][(S)], BUF[1], acc[0][1], 0, 0, 0); \
    acc[0][2] = __builtin_amdgcn_mfma_f32_16x16x32_f16(a[0][(S)], BUF[2], acc[0][2], 0, 0, 0); \
    acc[0][3] = __builtin_amdgcn_mfma_f32_16x16x32_f16(a[0][(S)], BUF[3], acc[0][3], 0, 0, 0); \
    acc[1][0] = __builtin_amdgcn_mfma_f32_16x16x32_f16(a[1][(S)], BUF[0], acc[1][0], 0, 0, 0); \
    acc[1][1] = __builtin_amdgcn_mfma_f32_16x16x32_f16(a[1][(S)], BUF[1], acc[1][1], 0, 0, 0); \
    acc[1][2] = __builtin_amdgcn_mfma_f32_16x16x32_f16(a[1][(S)], BUF[2], acc[1][2], 0, 0, 0); \
    acc[1][3] = __builtin_amdgcn_mfma_f32_16x16x32_f16(a[1][(S)], BUF[3], acc[1][3], 0, 0, 0); \
  } while (0)

#define ISSUE(BUF)                                                 \
  do {                                                             \
    GLDX4(BUF[0], p, 0); GLDX4(BUF[1], p, 1024);                   \
    GLDX4(BUF[2], p, 2048); GLDX4(BUF[3], p, 3072);                \
    p += 4096;                                                     \
  } while (0)

#define EPILOGUE(CTK)                                                         \
  do {                                                                        \
    const float* pe = &esq[(CTK) * 64 + col];                                 \
    _Pragma("unroll") for (int njj = 0; njj < 4; ++njj) {                     \
      const int code = (CTK) * 64 + njj * 16 + col;                           \
      const float sqv = pe[njj * 16];                                         \
      _Pragma("unroll") for (int mi = 0; mi < 2; ++mi)                        \
      _Pragma("unroll") for (int r = 0; r < 4; ++r) {                         \
        const float d = fmaf(-2.f, acc[mi][njj][r], sqv);                     \
        if (d < v1_[mi][r]) {                                                 \
          v3_[mi][r] = v2_[mi][r]; v2_[mi][r] = v1_[mi][r];                   \
          i2_[mi][r] = i1_[mi][r];                                            \
          v1_[mi][r] = d; i1_[mi][r] = code;                                  \
        } else if (d < v2_[mi][r]) {                                          \
          v3_[mi][r] = v2_[mi][r]; v2_[mi][r] = d; i2_[mi][r] = code;         \
        } else if (d < v3_[mi][r]) {                                          \
          v3_[mi][r] = d;                                                     \
        }                                                                     \
      }                                                                       \
    }                                                                         \
  } while (0)

  // main: chunks 0..14 — every step: wait(12), 8 MFMA, issue next group
  for (int ctk = 0; ctk < 15; ++ctk) {
#pragma unroll
    for (int mi = 0; mi < 2; ++mi)
#pragma unroll
      for (int nj = 0; nj < 4; ++nj) acc[mi][nj] = (f32x4){0.f, 0.f, 0.f, 0.f};
#pragma unroll
    for (int s = 0; s < 8; ++s) {
      VWAIT(12);  // step's group (oldest 4 of 16) has landed
      SB();
      if ((s & 3) == 0) { STEP_BODY(s, B[0]); ISSUE(B[0]); }
      else if ((s & 3) == 1) { STEP_BODY(s, B[1]); ISSUE(B[1]); }
      else if ((s & 3) == 2) { STEP_BODY(s, B[2]); ISSUE(B[2]); }
      else { STEP_BODY(s, B[3]); ISSUE(B[3]); }
    }
    EPILOGUE(ctk);
  }
  // peeled last chunk (ctk=15): compile-time tail waits, no over-issue
  {
#pragma unroll
    for (int mi = 0; mi < 2; ++mi)
#pragma unroll
      for (int nj = 0; nj < 4; ++nj) acc[mi][nj] = (f32x4){0.f, 0.f, 0.f, 0.f};
    // steps 120..127; issue allowed while step+4 <= 127 i.e. s <= 3
    VWAIT(12); SB(); STEP_BODY(0, B[0]); ISSUE(B[0]);
    VWAIT(12); SB(); STEP_BODY(1, B[1]); ISSUE(B[1]);
    VWAIT(12); SB(); STEP_BODY(2, B[2]); ISSUE(B[2]);
    VWAIT(12); SB(); STEP_BODY(3, B[3]); ISSUE(B[3]);
    VWAIT(12); SB(); STEP_BODY(4, B[0]);
    VWAIT(8);  SB(); STEP_BODY(5, B[1]);
    VWAIT(4);  SB(); STEP_BODY(6, B[2]);
    VWAIT(0);  SB(); STEP_BODY(7, B[3]);
    EPILOGUE(15);
  }
#undef STEP_BODY
#undef ISSUE
#undef EPILOGUE

  // cross-lane top-3 merge over the 16 code-columns (masks 1,2,4,8)
#pragma unroll
  for (int mi = 0; mi < 2; ++mi)
#pragma unroll
    for (int r = 0; r < 4; ++r) {
      float mv1 = v1_[mi][r], mv2 = v2_[mi][r], mv3 = v3_[mi][r];
      int mi1 = i1_[mi][r], mi2 = i2_[mi][r];
#pragma unroll
      for (int m = 1; m <= 8; m <<= 1) {
        const float ov1 = __shfl_xor(mv1, m, 64);
        const float ov2 = __shfl_xor(mv2, m, 64);
        const float ov3 = __shfl_xor(mv3, m, 64);
        const int oi1 = __shfl_xor(mi1, m, 64);
        const int oi2 = __shfl_xor(mi2, m, 64);
        const bool oW = (ov1 < mv1) || (ov1 == mv1 && oi1 < mi1);
        const float wv1 = oW ? ov1 : mv1, wv2 = oW ? ov2 : mv2, wv3 = oW ? ov3 : mv3;
        const int wi1 = oW ? oi1 : mi1, wi2 = oW ? oi2 : mi2;
        const float lv1 = oW ? mv1 : ov1, lv2 = oW ? mv2 : ov2;
        const int li1 = oW ? mi1 : oi1;
        const bool w2 = (wv2 < lv1) || (wv2 == lv1 && wi2 < li1);
        mv1 = wv1; mi1 = wi1;
        mv2 = w2 ? wv2 : lv1;
        mi2 = w2 ? wi2 : li1;
        mv3 = w2 ? fminf(wv3, lv1) : fminf(wv2, lv2);
      }
      if (col == 0) {
        const int t = tw + mi * 16 + kq * 4 + r;
        outIdxF[t] = (float)mi1;
        bestDist[t] = mv1;
        atomicAdd(&hist[mi1], 1);
        if (mv2 - mv1 < EPS) {
          const unsigned full = (mv3 - mv1 < EPS) ? 0x80000000u : 0u;
          const int pp = atomicAdd(fixCount, 1);
          fixList[pp * 2] = (unsigned)t | full;
          fixList[pp * 2 + 1] = (unsigned)mi2;
        }
      }
      i1_[mi][r] = mi1;  // merged, uniform across the kq group's 16 lanes
    }

  // fused gather: 32 tokens, index broadcast via shfl (no LDS, no barrier)
#pragma unroll
  for (int i = 0; i < 32; ++i) {
    const int id = __shfl(i1_[i >> 4][i & 3], ((i >> 2) & 3) * 16, 64);
    const float4 q = reinterpret_cast<const float4*>(&e[id * DIM])[lane];
    reinterpret_cast<float4*>(&outQ[(tw + i) * DIM])[lane] = q;
  }
}

// ---- fixup: pairwise exact check (common) or full rescan (rare) ----
__global__ __launch_bounds__(256) void vq_fixup(
    const float* __restrict__ x, const float* __restrict__ e,
    const int* __restrict__ fixCount, const unsigned int* __restrict__ fixList,
    float* __restrict__ outIdxF, float* __restrict__ outQ,
    float* __restrict__ bestDist, int* __restrict__ hist) {
  const int n = *fixCount;
  const int tid = threadIdx.x;
  __shared__ float xrow[256];
  __shared__ float rv[4];
  __shared__ int ri[4];
  __shared__ int sOld, sFi;
  for (int it = blockIdx.x; it < n; it += gridDim.x) {
    const unsigned e0 = fixList[it * 2];
    const int t = (int)(e0 & 0x3FFFFFFFu);
    const bool full = (e0 >> 31) != 0u;
    if (!full) {
      if (tid < 64) {
        const int i1 = (int)outIdxF[t];
        const int i2 = (int)fixList[it * 2 + 1];
        const float4 xv = reinterpret_cast<const float4*>(&x[t * DIM])[tid];
        const float4 e1 = reinterpret_cast<const float4*>(&e[i1 * DIM])[tid];
        const float4 e2 = reinterpret_cast<const float4*>(&e[i2 * DIM])[tid];
        float d1 = (xv.x - e1.x) * (xv.x - e1.x) + (xv.y - e1.y) * (xv.y - e1.y) +
                   (xv.z - e1.z) * (xv.z - e1.z) + (xv.w - e1.w) * (xv.w - e1.w);
        float d2 = (xv.x - e2.x) * (xv.x - e2.x) + (xv.y - e2.y) * (xv.y - e2.y) +
                   (xv.z - e2.z) * (xv.z - e2.z) + (xv.w - e2.w) * (xv.w - e2.w);
#pragma unroll
        for (int m = 32; m > 0; m >>= 1) {
          d1 += __shfl_xor(d1, m, 64);
          d2 += __shfl_xor(d2, m, 64);
        }
        const bool swap2 = (d2 < d1) || (d2 == d1 && i2 < i1);
        const int wIdx = swap2 ? i2 : i1;
        const float wD = swap2 ? d2 : d1;
        if (tid == 0) {
          bestDist[t] = wD;
          if (wIdx != i1) {
            atomicSub(&hist[i1], 1);
            atomicAdd(&hist[wIdx], 1);
            outIdxF[t] = (float)wIdx;
          }
        }
        if (swap2) {
          const float4 q = reinterpret_cast<const float4*>(&e[wIdx * DIM])[tid];
          reinterpret_cast<float4*>(&outQ[t * DIM])[tid] = q;
        }
      }
    } else {
      __syncthreads();
      if (tid < 64) ((float4*)xrow)[tid] = ((const float4*)&x[t * DIM])[tid];
      __syncthreads();
      float bv = 3.4e38f; int bi = 0;
      for (int c = tid; c < KC; c += 256) {
        float s = 0.f;
#pragma unroll
        for (int d = 0; d < DIM; d += 4) {
          const float4 ev = *(const float4*)&e[c * DIM + d];
          const float d0 = xrow[d] - ev.x, d1 = xrow[d + 1] - ev.y;
          const float d2 = xrow[d + 2] - ev.z, d3 = xrow[d + 3] - ev.w;
          s += d0 * d0 + d1 * d1 + d2 * d2 + d3 * d3;
        }
        if (s < bv) { bv = s; bi = c; }
      }
#pragma unroll
      for (int m = 1; m <= 32; m <<= 1) {
        const float ob = __shfl_xor(bv, m, 64);
        const int oi = __shfl_xor(bi, m, 64);
        if (ob < bv || (ob == bv && oi < bi)) { bv = ob; bi = oi; }
      }
      const int lane = tid & 63, wv = tid >> 6;
      if (lane == 0) { rv[wv] = bv; ri[wv] = bi; }
      __syncthreads();
      if (tid == 0) {
        float fb = rv[0]; int fi = ri[0];
        for (int k = 1; k < 4; ++k)
          if (rv[k] < fb || (rv[k] == fb && ri[k] < fi)) { fb = rv[k]; fi = ri[k]; }
        sOld = (int)outIdxF[t];
        sFi = fi;
        bestDist[t] = fb;
        if (fi != sOld) {
          atomicSub(&hist[sOld], 1);
          atomicAdd(&hist[fi], 1);
          outIdxF[t] = (float)fi;
        }
      }
      __syncthreads();
      if (sFi != sOld) outQ[t * DIM + tid] = e[sFi * DIM + tid];
      __syncthreads();
    }
  }
}

// ---- final scalars: loss from xsq+bestDist; perplexity from hist ----
__global__ __launch_bounds__(1024) void vq_final(
    const int* __restrict__ hist, const float* __restrict__ xsq,
    const float* __restrict__ bestDist, float* __restrict__ outLoss,
    float* __restrict__ outPerp) {
  const int tid = threadIdx.x;
  float ls = 0.f;
  for (int i = 0; i < 64; ++i) {
    const int t = tid + i * 1024;
    ls += xsq[t] + bestDist[t];
  }
  const float p = (float)hist[tid] * (1.f / 65536.f);
  float ent = p * logf(p + 1e-10f);
#pragma unroll
  for (int o = 32; o > 0; o >>= 1) {
    ls += __shfl_down(ls, o, 64);
    ent += __shfl_down(ent, o, 64);
  }
  __shared__ float lbuf[16], ebuf[16];
  const int lane = tid & 63, wv = tid >> 6;
  if (lane == 0) { lbuf[wv] = ls; ebuf[wv] = ent; }
  __syncthreads();
  if (tid == 0) {
    float L = 0.f, E = 0.f;
    for (int i = 0; i < 16; ++i) { L += lbuf[i]; E += ebuf[i]; }
    *outLoss = 0.25f * (L / 16777216.f);
    *outPerp = expf(-E);
  }
}

extern "C" void kernel_launch(void* const* d_in, const int* in_sizes, int n_in,
                              void* d_out, int out_size, void* d_ws, size_t ws_size,
                              hipStream_t stream) {
  const float* x = (const float*)d_in[0];  // [65536, 256]
  const float* e = (const float*)d_in[1];  // [1024, 256]
  float* out = (float*)d_out;
  float* outQ = out;                 // 16777216 floats
  float* outLoss = out + 16777216;
  float* outPerp = out + 16777217;
  float* outIdxF = out + 16777218;   // 65536 floats

  char* ws = (char*)d_ws;
  int*   hist     = (int*)ws;                     // 4 KB
  float* esq      = (float*)(ws + 4096);          // 4 KB
  float* xsq      = (float*)(ws + 8192);          // 256 KB
  float* bestDist = (float*)(ws + 270336);        // 256 KB
  int*   fixCount = (int*)(ws + 532480);          // 16 B
  unsigned int* fixList = (unsigned int*)(ws + 532496);  // 512 KB (2/entry)
  unsigned short* e_f16 = (unsigned short*)(ws + 1056784);  // 512 KB
  // total ws use ~1.57 MB

  vq_prep_e<<<128, 256, 0, stream>>>(e, e_f16, esq, hist, fixCount);
  vq_argmin<<<NTOK / 128, 256, 0, stream>>>(x, e_f16, esq, e, outIdxF, outQ,
                                            bestDist, xsq, hist, fixCount, fixList);
  vq_fixup<<<256, 256, 0, stream>>>(x, e, fixCount, fixList, outIdxF, outQ,
                                    bestDist, hist);
  vq_final<<<1, 1024, 0, stream>>>(hist, xsq, bestDist, outLoss, outPerp);
}